// Round 14
// baseline (104.896 us; speedup 1.0000x reference)
//
#include <hip/hip_runtime.h>

// Problem constants
#define HWSZ 65536             // 256*256
#define PLANE (3 * HWSZ)       // one batch's [3,H,W]
#define OUTSTRIDE (8 * PLANE)  // one full output tensor [8,3,256,256]
#define MAGIC 0x13572468       // != 0xAAAAAAAA ws poison

// ---------------------------------------------------------------------------
// Node 1: proj only. 32 blocks x 384 = (s = 8 K-splits) x (q = 48 quads).
// 32-deep float4 weight batches (512 B/thread in flight -> 2 dependent rounds).
__global__ __launch_bounds__(384) void k_proj(
    const float* __restrict__ f, const float* __restrict__ bf,
    const float* __restrict__ pw1, const float* __restrict__ pb1,
    const float* __restrict__ pw2, const float* __restrict__ pb2,
    float* __restrict__ ws) {
  __shared__ float smem[2304];
  int t = threadIdx.x, blk = blockIdx.x;
  float* outs = ws;  // [4,8,192]

  int k = blk >> 3, b = blk & 7;
  int q = t % 48, s = t / 48;  // s in 0..7
  float* sf  = smem;           // 512
  float* red = smem + 512;     // 8*192
  float* sh  = smem + 2048;    // 192

  const float* feat = ((k & 1) ? bf : f) + b * 512;
  for (int i = t; i < 512; i += 384) sf[i] = feat[i];
  __syncthreads();

  {  // 512 -> 192, K slice s*64..+64 in 2 rounds of 32
    const float4* w = (const float4*)(pw1 + (size_t)k * (512 * 192));
    float4 acc = {0.f, 0.f, 0.f, 0.f};
    int i0 = s * 64;
    for (int r = 0; r < 2; ++r) {
      float4 wv[32];
#pragma unroll
      for (int j = 0; j < 32; ++j)
        wv[j] = w[(size_t)(i0 + r * 32 + j) * 48 + q];
#pragma unroll
      for (int j = 0; j < 32; ++j) {
        float v = sf[i0 + r * 32 + j];
        acc.x = fmaf(v, wv[j].x, acc.x); acc.y = fmaf(v, wv[j].y, acc.y);
        acc.z = fmaf(v, wv[j].z, acc.z); acc.w = fmaf(v, wv[j].w, acc.w);
      }
    }
    ((float4*)(red + s * 192))[q] = acc;
  }
  __syncthreads();
  if (t < 192) {
    float a = pb1[k * 192 + t];
#pragma unroll
    for (int s2 = 0; s2 < 8; ++s2) a += red[s2 * 192 + t];
    sh[t] = fmaxf(a, 0.f);
  }
  __syncthreads();
  {  // 192 -> 192, K slice s*24..+24 in 1 round of 24
    const float4* w = (const float4*)(pw2 + (size_t)k * (192 * 192));
    float4 acc = {0.f, 0.f, 0.f, 0.f};
    int i0 = s * 24;
    float4 wv[24];
#pragma unroll
    for (int j = 0; j < 24; ++j)
      wv[j] = w[(size_t)(i0 + j) * 48 + q];
#pragma unroll
    for (int j = 0; j < 24; ++j) {
      float v = sh[i0 + j];
      acc.x = fmaf(v, wv[j].x, acc.x); acc.y = fmaf(v, wv[j].y, acc.y);
      acc.z = fmaf(v, wv[j].z, acc.z); acc.w = fmaf(v, wv[j].w, acc.w);
    }
    ((float4*)(red + s * 192))[q] = acc;
  }
  __syncthreads();
  if (t < 192) {
    float a = pb2[k * 192 + t];
#pragma unroll
    for (int s2 = 0; s2 < 8; ++s2) a += red[s2 * 192 + t];
    outs[(k * 8 + b) * 192 + t] = a;
  }
}

// ---------------------------------------------------------------------------
// Node 2: render + embedded fcat. Grid (32,8) x 256.
//  Blocks bx<4: fcat B1 (hc quarter, flagB1) -> B2 (param quarter, flagB2),
//    R12-proven 1-level/4-flag handshakes.
//  All blocks: gray LUT (needs only outs) -> render o1,o2 (2/3 of stores)
//    -> poll 4 flagB2 of b (long since set) -> color LUT -> render o0.
__global__ __launch_bounds__(256) void k_render(
    const float* __restrict__ x, const float* __restrict__ fw1,
    const float* __restrict__ fb1, const float* __restrict__ fw2,
    const float* __restrict__ fb2, float* __restrict__ ws,
    float* __restrict__ out) {
  int b = blockIdx.y, bx = blockIdx.x, t = threadIdx.x;
  int wave = t >> 6, lane = t & 63;
  float* outs  = ws;          // [4,8,192]
  float* hc    = ws + 12288;  // [8,192]
  float* param = ws + 13824;  // [8,192]
  int* fbase = (int*)(ws + 16384);
  // flagB1[i] = fbase[i*16], flagB2[i] = fbase[(32+i)*16], i = c4*8+b

  __shared__ float smem[1344];  // sc(576)+red(768) | tab(1152 floats)
  float2* tab = (float2*)smem;

  // prefetch x
  int s4a = bx * 512 + t, s4b = s4a + 256;
  const float* xb = x + (size_t)b * PLANE;
  float4 vr0 = ((const float4*)(xb))[s4a];
  float4 vr1 = ((const float4*)(xb))[s4b];
  float4 vg0 = ((const float4*)(xb + HWSZ))[s4a];
  float4 vg1 = ((const float4*)(xb + HWSZ))[s4b];
  float4 vb0 = ((const float4*)(xb + 2 * HWSZ))[s4a];
  float4 vb1 = ((const float4*)(xb + 2 * HWSZ))[s4b];

  if (bx < 4) {
    // ---- fcat B1: hc[b, bx*48 .. +48] ----
    int ob2 = bx * 48;
    float* sc  = smem;         // 576
    float* red = smem + 576;   // 16*48
    for (int idx = t; idx < 576; idx += 256) {
      float v;
      if (idx < 192)      v = outs[(0 * 8 + b) * 192 + idx];
      else if (idx < 384) v = outs[(1 * 8 + b) * 192 + (idx - 192)];
      else                v = outs[(2 * 8 + b) * 192 + (idx - 384)] +
                              outs[(3 * 8 + b) * 192 + (idx - 384)];
      sc[idx] = v;
    }
    __syncthreads();
    if (t < 192) {
      int q = t % 12, s = t / 12;  // s in 0..15, 36-deep K slices
      const float4* w = (const float4*)fw1;
      float4 wv[36];
      int i0 = s * 36;
#pragma unroll
      for (int j = 0; j < 36; ++j)
        wv[j] = w[(size_t)(i0 + j) * 48 + bx * 12 + q];
      float4 acc = {0.f, 0.f, 0.f, 0.f};
#pragma unroll
      for (int j = 0; j < 36; ++j) {
        float v = sc[i0 + j];
        acc.x = fmaf(v, wv[j].x, acc.x); acc.y = fmaf(v, wv[j].y, acc.y);
        acc.z = fmaf(v, wv[j].z, acc.z); acc.w = fmaf(v, wv[j].w, acc.w);
      }
      ((float4*)(red + s * 48))[q] = acc;
    }
    __syncthreads();
    if (t < 48) {
      float a = fb1[ob2 + t];
#pragma unroll
      for (int s2 = 0; s2 < 16; ++s2) a += red[s2 * 48 + t];
      hc[b * 192 + ob2 + t] = fmaxf(a, 0.f);
    }
    __syncthreads();
    if (t == 0) {
      __threadfence();
      atomicExch(&fbase[(bx * 8 + b) * 16], MAGIC);
    }

    // ---- fcat B2: param[b, bx*48 .. +48] ----
    if (t < 4) {
      while (atomicAdd(&fbase[(t * 8 + b) * 16], 0) != MAGIC)
        __builtin_amdgcn_s_sleep(2);
    }
    __syncthreads();
    if (t == 0) __threadfence();  // acquire
    __syncthreads();
    float* sh = smem;  // 192 (red unused now, reuse base)
    if (t < 192) sh[t] = hc[b * 192 + t];
    __syncthreads();
    if (t < 192) {
      int q = t % 12, s = t / 12;  // 12-deep K slices
      const float4* w = (const float4*)fw2;
      float4 wv[12];
      int i0 = s * 12;
#pragma unroll
      for (int j = 0; j < 12; ++j)
        wv[j] = w[(size_t)(i0 + j) * 48 + bx * 12 + q];
      float4 acc = {0.f, 0.f, 0.f, 0.f};
#pragma unroll
      for (int j = 0; j < 12; ++j) {
        float v = sh[i0 + j];
        acc.x = fmaf(v, wv[j].x, acc.x); acc.y = fmaf(v, wv[j].y, acc.y);
        acc.z = fmaf(v, wv[j].z, acc.z); acc.w = fmaf(v, wv[j].w, acc.w);
      }
      ((float4*)(smem + 576 + s * 48))[q] = acc;
    }
    __syncthreads();
    if (t < 48) {
      float a = fb2[ob2 + t];
#pragma unroll
      for (int s2 = 0; s2 < 16; ++s2) a += smem[576 + s2 * 48 + t];
      param[b * 192 + ob2 + t] = a;
    }
    __syncthreads();
    if (t == 0) {
      __threadfence();
      atomicExch(&fbase[(32 + bx * 8 + b) * 16], MAGIC);
    }
    __syncthreads();
  }

  // ---- gray LUT (curves 3..8; needs only outs) ----
  auto build = [&](int cur) {
    int oi = cur / 3, c = cur - oi * 3;
    const float* src = (oi == 0) ? param + b * 192 + c * 64
                                 : outs + ((oi - 1) * 8 + b) * 192 + c * 64;
    float p = src[lane];
    float v = p;  // inclusive scan
#pragma unroll
    for (int d = 1; d < 64; d <<= 1) {
      float n = __shfl_up(v, d, 64);
      if (lane >= d) v += n;
    }
    float total = __shfl(v, 63, 64);
    float norm = 64.f / (total + 1e-30f);
    tab[cur * 64 + lane] = make_float2((v - p) * 0.015625f * norm, p * norm);
  };
  for (int cur = 3 + wave; cur < 9; cur += 4) build(cur);
  __syncthreads();

  auto idx_of = [&](float v, int& kk, float& tt) {
    int k = (int)(v * 64.f);
    k = k < 0 ? 0 : (k > 63 ? 63 : k);
    kk = k;
    tt = v - (float)k * 0.015625f;
  };
  auto evk = [&](int cur, int k, float tt) -> float {
    float2 e = tab[cur * 64 + k];
    return fmaf(tt, e.y, e.x);
  };
  auto ev4 = [&](int cur, float4 v) -> float4 {
    int k; float tt; float4 r;
    idx_of(v.x, k, tt); r.x = evk(cur, k, tt);
    idx_of(v.y, k, tt); r.y = evk(cur, k, tt);
    idx_of(v.z, k, tt); r.z = evk(cur, k, tt);
    idx_of(v.w, k, tt); r.w = evk(cur, k, tt);
    return r;
  };

  float* o0 = out + (size_t)b * PLANE;
  float* o1 = out + OUTSTRIDE + (size_t)b * PLANE;
  float* o2 = out + 2 * OUTSTRIDE + (size_t)b * PLANE;

  float4 gr0, gr1;
  {
    gr0.x = fmaf(0.299f, vr0.x, fmaf(0.587f, vg0.x, 0.114f * vb0.x));
    gr0.y = fmaf(0.299f, vr0.y, fmaf(0.587f, vg0.y, 0.114f * vb0.y));
    gr0.z = fmaf(0.299f, vr0.z, fmaf(0.587f, vg0.z, 0.114f * vb0.z));
    gr0.w = fmaf(0.299f, vr0.w, fmaf(0.587f, vg0.w, 0.114f * vb0.w));
    gr1.x = fmaf(0.299f, vr1.x, fmaf(0.587f, vg1.x, 0.114f * vb1.x));
    gr1.y = fmaf(0.299f, vr1.y, fmaf(0.587f, vg1.y, 0.114f * vb1.y));
    gr1.z = fmaf(0.299f, vr1.z, fmaf(0.587f, vg1.z, 0.114f * vb1.z));
    gr1.w = fmaf(0.299f, vr1.w, fmaf(0.587f, vg1.w, 0.114f * vb1.w));
  }

  auto gray_out = [&](int s4, float4 gr) {
    int kx, ky, kz, kw; float tx, ty, tz, tw;
    idx_of(gr.x, kx, tx); idx_of(gr.y, ky, ty);
    idx_of(gr.z, kz, tz); idx_of(gr.w, kw, tw);
#pragma unroll
    for (int c = 0; c < 3; ++c) {
      float4 r;
      r.x = evk(3 + c, kx, tx); r.y = evk(3 + c, ky, ty);
      r.z = evk(3 + c, kz, tz); r.w = evk(3 + c, kw, tw);
      ((float4*)(o1 + c * HWSZ))[s4] = r;
    }
#pragma unroll
    for (int c = 0; c < 3; ++c) {
      float4 r;
      r.x = evk(6 + c, kx, tx); r.y = evk(6 + c, ky, ty);
      r.z = evk(6 + c, kz, tz); r.w = evk(6 + c, kw, tw);
      ((float4*)(o2 + c * HWSZ))[s4] = r;
    }
  };
  gray_out(s4a, gr0);
  gray_out(s4b, gr1);

  // ---- wait for param (long since ready), color LUT, render o0 ----
  if (t < 4) {
    while (atomicAdd(&fbase[(32 + t * 8 + b) * 16], 0) != MAGIC)
      __builtin_amdgcn_s_sleep(2);
  }
  __syncthreads();
  if (t == 0) __threadfence();  // acquire
  __syncthreads();
  for (int cur = wave; cur < 3; cur += 4) build(cur);
  __syncthreads();

  ((float4*)(o0))[s4a]            = ev4(0, vr0);
  ((float4*)(o0))[s4b]            = ev4(0, vr1);
  ((float4*)(o0 + HWSZ))[s4a]     = ev4(1, vg0);
  ((float4*)(o0 + HWSZ))[s4b]     = ev4(1, vg1);
  ((float4*)(o0 + 2 * HWSZ))[s4a] = ev4(2, vb0);
  ((float4*)(o0 + 2 * HWSZ))[s4b] = ev4(2, vb1);
}

// ---------------------------------------------------------------------------
extern "C" void kernel_launch(void* const* d_in, const int* in_sizes, int n_in,
                              void* d_out, int out_size, void* d_ws, size_t ws_size,
                              hipStream_t stream) {
  const float* x   = (const float*)d_in[0];
  const float* f   = (const float*)d_in[1];
  const float* bf  = (const float*)d_in[2];
  const float* pw1 = (const float*)d_in[3];
  const float* pb1 = (const float*)d_in[4];
  const float* pw2 = (const float*)d_in[5];
  const float* pb2 = (const float*)d_in[6];
  const float* fw1 = (const float*)d_in[7];
  const float* fb1 = (const float*)d_in[8];
  const float* fw2 = (const float*)d_in[9];
  const float* fb2 = (const float*)d_in[10];
  float* out = (float*)d_out;
  float* ws  = (float*)d_ws;

  k_proj<<<32, 384, 0, stream>>>(f, bf, pw1, pb1, pw2, pb2, ws);
  dim3 grid(32, 8);
  k_render<<<grid, 256, 0, stream>>>(x, fw1, fb1, fw2, fb2, ws, out);
}

// Round 15
// 99.989 us; speedup vs baseline: 1.0491x; 1.0491x over previous
//
#include <hip/hip_runtime.h>

// Problem constants
#define HWSZ 65536             // 256*256
#define PLANE (3 * HWSZ)       // one batch's [3,H,W]
#define OUTSTRIDE (8 * PLANE)  // one full output tensor [8,3,256,256]
#define MAGIC 0x13572468       // != 0xAAAAAAAA ws poison

// ---------------------------------------------------------------------------
// Fused MLP: 32 blocks x 384 (R12/R13 structure; phase-A weight batches
// widened to 32-deep float4 -> 2 dependent rounds in layer 1, 1 in layer 2).
__global__ __launch_bounds__(384) void k_mlp(
    const float* __restrict__ f, const float* __restrict__ bf,
    const float* __restrict__ pw1, const float* __restrict__ pb1,
    const float* __restrict__ pw2, const float* __restrict__ pb2,
    const float* __restrict__ fw1, const float* __restrict__ fb1,
    const float* __restrict__ fw2, const float* __restrict__ fb2,
    float* __restrict__ ws) {
  __shared__ float smem[2304];
  int t = threadIdx.x, blk = blockIdx.x;

  float* outs  = ws;          // [4,8,192]
  float* hc    = ws + 12288;  // [8,192]
  float* param = ws + 13824;  // [8,192]
  int* fbase = (int*)(ws + 16384);
  // flagA[i] = fbase[i*16] (i<32); flagB[i] = fbase[(64+i)*16]

  // ======== Phase A: proj for (k,b) ========
  int k = blk >> 3, b = blk & 7;
  {
    int q = t % 48, s = t / 48;  // s in 0..7
    float* sf  = smem;           // 512
    float* red = smem + 512;     // 8*192
    float* sh  = smem + 2048;    // 192

    const float* feat = ((k & 1) ? bf : f) + b * 512;
    for (int i = t; i < 512; i += 384) sf[i] = feat[i];
    __syncthreads();

    {  // 512 -> 192, K slice s*64..+64 in 2 rounds of 32
      const float4* w = (const float4*)(pw1 + (size_t)k * (512 * 192));
      float4 acc = {0.f, 0.f, 0.f, 0.f};
      int i0 = s * 64;
      for (int r = 0; r < 2; ++r) {
        float4 wv[32];
#pragma unroll
        for (int j = 0; j < 32; ++j)
          wv[j] = w[(size_t)(i0 + r * 32 + j) * 48 + q];
#pragma unroll
        for (int j = 0; j < 32; ++j) {
          float v = sf[i0 + r * 32 + j];
          acc.x = fmaf(v, wv[j].x, acc.x); acc.y = fmaf(v, wv[j].y, acc.y);
          acc.z = fmaf(v, wv[j].z, acc.z); acc.w = fmaf(v, wv[j].w, acc.w);
        }
      }
      ((float4*)(red + s * 192))[q] = acc;
    }
    __syncthreads();
    if (t < 192) {
      float a = pb1[k * 192 + t];
#pragma unroll
      for (int s2 = 0; s2 < 8; ++s2) a += red[s2 * 192 + t];
      sh[t] = fmaxf(a, 0.f);
    }
    __syncthreads();
    {  // 192 -> 192, K slice s*24..+24 in 1 round of 24
      const float4* w = (const float4*)(pw2 + (size_t)k * (192 * 192));
      float4 acc = {0.f, 0.f, 0.f, 0.f};
      int i0 = s * 24;
      float4 wv[24];
#pragma unroll
      for (int j = 0; j < 24; ++j)
        wv[j] = w[(size_t)(i0 + j) * 48 + q];
#pragma unroll
      for (int j = 0; j < 24; ++j) {
        float v = sh[i0 + j];
        acc.x = fmaf(v, wv[j].x, acc.x); acc.y = fmaf(v, wv[j].y, acc.y);
        acc.z = fmaf(v, wv[j].z, acc.z); acc.w = fmaf(v, wv[j].w, acc.w);
      }
      ((float4*)(red + s * 192))[q] = acc;
    }
    __syncthreads();
    if (t < 192) {
      float a = pb2[k * 192 + t];
#pragma unroll
      for (int s2 = 0; s2 < 8; ++s2) a += red[s2 * 192 + t];
      outs[(k * 8 + b) * 192 + t] = a;
    }
    __syncthreads();  // drain stores before fence
    if (t == 0) {
      __threadfence();
      atomicExch(&fbase[blk * 16], MAGIC);
    }
  }

  // ======== Phase B1: fc1 for (b2 = blk&7, quarter c4 = blk>>3) ========
  int b2 = blk & 7, c4 = blk >> 3, ob2 = c4 * 48;
  int q = t % 12, s = t / 12;  // s in 0..31

  // prefetch fw1 slice (independent of outs) BEFORE the spin
  float4 wv1[18];
  {
    const float4* w = (const float4*)fw1;
    int i0 = s * 18;
#pragma unroll
    for (int j = 0; j < 18; ++j)
      wv1[j] = w[(size_t)(i0 + j) * 48 + (ob2 >> 2) + q];
  }

  if (t < 4) {
    while (atomicAdd(&fbase[(t * 8 + b2) * 16], 0) != MAGIC)
      __builtin_amdgcn_s_sleep(2);
  }
  __syncthreads();
  if (t == 0) __threadfence();  // acquire
  __syncthreads();

  {
    float* sc  = smem;           // 576
    float* red = smem + 576;     // 32*48
    for (int idx = t; idx < 576; idx += 384) {
      float v;
      if (idx < 192)      v = outs[(0 * 8 + b2) * 192 + idx];
      else if (idx < 384) v = outs[(1 * 8 + b2) * 192 + (idx - 192)];
      else                v = outs[(2 * 8 + b2) * 192 + (idx - 384)] +
                              outs[(3 * 8 + b2) * 192 + (idx - 384)];
      sc[idx] = v;
    }
    __syncthreads();
    float4 acc = {0.f, 0.f, 0.f, 0.f};
    int i0 = s * 18;
#pragma unroll
    for (int j = 0; j < 18; ++j) {
      float v = sc[i0 + j];
      acc.x = fmaf(v, wv1[j].x, acc.x); acc.y = fmaf(v, wv1[j].y, acc.y);
      acc.z = fmaf(v, wv1[j].z, acc.z); acc.w = fmaf(v, wv1[j].w, acc.w);
    }
    ((float4*)(red + s * 48))[q] = acc;
    __syncthreads();
    if (t < 48) {
      float a = fb1[ob2 + t];
#pragma unroll
      for (int s2 = 0; s2 < 32; ++s2) a += red[s2 * 48 + t];
      hc[b2 * 192 + ob2 + t] = fmaxf(a, 0.f);
    }
    __syncthreads();
    if (t == 0) {
      __threadfence();
      atomicExch(&fbase[(64 + blk) * 16], MAGIC);
    }
  }

  // ======== Phase B2: fc2, same (b2, c4) ========
  // prefetch fw2 slice before the spin
  float4 wv2[6];
  {
    const float4* w = (const float4*)fw2;
    int i0 = s * 6;
#pragma unroll
    for (int j = 0; j < 6; ++j)
      wv2[j] = w[(size_t)(i0 + j) * 48 + (ob2 >> 2) + q];
  }

  if (t < 4) {
    while (atomicAdd(&fbase[(64 + t * 8 + b2) * 16], 0) != MAGIC)
      __builtin_amdgcn_s_sleep(2);
  }
  __syncthreads();
  if (t == 0) __threadfence();  // acquire
  __syncthreads();

  {
    float* sh  = smem;           // 192
    float* red = smem + 576;     // 32*48
    if (t < 192) sh[t] = hc[b2 * 192 + t];
    __syncthreads();
    float4 acc = {0.f, 0.f, 0.f, 0.f};
    int i0 = s * 6;
#pragma unroll
    for (int j = 0; j < 6; ++j) {
      float v = sh[i0 + j];
      acc.x = fmaf(v, wv2[j].x, acc.x); acc.y = fmaf(v, wv2[j].y, acc.y);
      acc.z = fmaf(v, wv2[j].z, acc.z); acc.w = fmaf(v, wv2[j].w, acc.w);
    }
    ((float4*)(red + s * 48))[q] = acc;
    __syncthreads();
    if (t < 48) {
      float a = fb2[ob2 + t];
#pragma unroll
      for (int s2 = 0; s2 < 32; ++s2) a += red[s2 * 48 + t];
      param[b2 * 192 + ob2 + t] = a;
    }
  }
}

// ---------------------------------------------------------------------------
// Render: 256 blocks (32,8) x 256 threads, 2 float4 per thread per channel.
// LUT entry e[k] = {S_k*norm/64, p_k*norm}. Gray curves share k/tt.
__global__ __launch_bounds__(256) void k_render(
    const float* __restrict__ x, const float* __restrict__ ws,
    float* __restrict__ out) {
  int b = blockIdx.y, t = threadIdx.x;
  int wave = t >> 6, lane = t & 63;
  const float* outs  = ws;
  const float* param = ws + 13824;
  __shared__ float2 tab[576];

  // prefetch both x float4 groups
  int s4a = blockIdx.x * 512 + t, s4b = s4a + 256;
  const float* xb = x + (size_t)b * PLANE;
  float4 vr0 = ((const float4*)(xb))[s4a];
  float4 vr1 = ((const float4*)(xb))[s4b];
  float4 vg0 = ((const float4*)(xb + HWSZ))[s4a];
  float4 vg1 = ((const float4*)(xb + HWSZ))[s4b];
  float4 vb0 = ((const float4*)(xb + 2 * HWSZ))[s4a];
  float4 vb1 = ((const float4*)(xb + 2 * HWSZ))[s4b];

  for (int cur = wave; cur < 9; cur += 4) {
    int oi = cur / 3, c = cur - oi * 3;
    const float* src = (oi == 0) ? param + b * 192 + c * 64
                                 : outs + ((oi - 1) * 8 + b) * 192 + c * 64;
    float p = src[lane];
    float v = p;  // inclusive scan
#pragma unroll
    for (int d = 1; d < 64; d <<= 1) {
      float n = __shfl_up(v, d, 64);
      if (lane >= d) v += n;
    }
    float total = __shfl(v, 63, 64);
    float norm = 64.f / (total + 1e-30f);
    tab[cur * 64 + lane] = make_float2((v - p) * 0.015625f * norm, p * norm);
  }
  __syncthreads();

  auto idx_of = [&](float v, int& kk, float& tt) {
    int k = (int)(v * 64.f);
    k = k < 0 ? 0 : (k > 63 ? 63 : k);
    kk = k;
    tt = v - (float)k * 0.015625f;
  };
  auto evk = [&](int cur, int k, float tt) -> float {
    float2 e = tab[cur * 64 + k];
    return fmaf(tt, e.y, e.x);
  };
  auto ev4 = [&](int cur, float4 v) -> float4 {
    int k; float tt; float4 r;
    idx_of(v.x, k, tt); r.x = evk(cur, k, tt);
    idx_of(v.y, k, tt); r.y = evk(cur, k, tt);
    idx_of(v.z, k, tt); r.z = evk(cur, k, tt);
    idx_of(v.w, k, tt); r.w = evk(cur, k, tt);
    return r;
  };

  float* o0 = out + (size_t)b * PLANE;
  float* o1 = out + OUTSTRIDE + (size_t)b * PLANE;
  float* o2 = out + 2 * OUTSTRIDE + (size_t)b * PLANE;

  auto process = [&](int s4, float4 vr, float4 vg, float4 vb) {
    float4 gr;
    gr.x = fmaf(0.299f, vr.x, fmaf(0.587f, vg.x, 0.114f * vb.x));
    gr.y = fmaf(0.299f, vr.y, fmaf(0.587f, vg.y, 0.114f * vb.y));
    gr.z = fmaf(0.299f, vr.z, fmaf(0.587f, vg.z, 0.114f * vb.z));
    gr.w = fmaf(0.299f, vr.w, fmaf(0.587f, vg.w, 0.114f * vb.w));

    ((float4*)(o0))[s4]            = ev4(0, vr);
    ((float4*)(o0 + HWSZ))[s4]     = ev4(1, vg);
    ((float4*)(o0 + 2 * HWSZ))[s4] = ev4(2, vb);

    // gray: shared piece index across curves 3..8
    int kx, ky, kz, kw; float tx, ty, tz, tw;
    idx_of(gr.x, kx, tx); idx_of(gr.y, ky, ty);
    idx_of(gr.z, kz, tz); idx_of(gr.w, kw, tw);
#pragma unroll
    for (int c = 0; c < 3; ++c) {
      float4 r;
      r.x = evk(3 + c, kx, tx); r.y = evk(3 + c, ky, ty);
      r.z = evk(3 + c, kz, tz); r.w = evk(3 + c, kw, tw);
      ((float4*)(o1 + c * HWSZ))[s4] = r;
    }
#pragma unroll
    for (int c = 0; c < 3; ++c) {
      float4 r;
      r.x = evk(6 + c, kx, tx); r.y = evk(6 + c, ky, ty);
      r.z = evk(6 + c, kz, tz); r.w = evk(6 + c, kw, tw);
      ((float4*)(o2 + c * HWSZ))[s4] = r;
    }
  };

  process(s4a, vr0, vg0, vb0);
  process(s4b, vr1, vg1, vb1);
}

// ---------------------------------------------------------------------------
extern "C" void kernel_launch(void* const* d_in, const int* in_sizes, int n_in,
                              void* d_out, int out_size, void* d_ws, size_t ws_size,
                              hipStream_t stream) {
  const float* x   = (const float*)d_in[0];
  const float* f   = (const float*)d_in[1];
  const float* bf  = (const float*)d_in[2];
  const float* pw1 = (const float*)d_in[3];
  const float* pb1 = (const float*)d_in[4];
  const float* pw2 = (const float*)d_in[5];
  const float* pb2 = (const float*)d_in[6];
  const float* fw1 = (const float*)d_in[7];
  const float* fb1 = (const float*)d_in[8];
  const float* fw2 = (const float*)d_in[9];
  const float* fb2 = (const float*)d_in[10];
  float* out = (float*)d_out;
  float* ws  = (float*)d_ws;

  k_mlp<<<32, 384, 0, stream>>>(f, bf, pw1, pb1, pw2, pb2, fw1, fb1, fw2,
                                fb2, ws);
  dim3 grid(32, 8);
  k_render<<<grid, 256, 0, stream>>>(x, ws, out);
}